// Round 1
// baseline (1911.593 us; speedup 1.0000x reference)
//
#include <hip/hip_runtime.h>
#include <hip/hip_bf16.h>
#include <stdint.h>

// ---------------------------------------------------------------------------
// Transformer: 6 layers of {BN -> (qk,v GEMM) -> attn -> o-proj(+res)} then
// {BN -> W1 -> BN -> GELU -> W2(+res)}.  B=64 N=196 DIM=768 HEADS=8 DH=64 DV=112
// Strategy: fp32 residual stream + BN stats; bf16 MFMA GEMMs (16x16x32),
// weights pre-transposed to N x K bf16 once per call.
// ---------------------------------------------------------------------------

typedef __bf16 bf16x8 __attribute__((ext_vector_type(8)));
typedef __bf16 bf16x4 __attribute__((ext_vector_type(4)));
typedef float  f32x4  __attribute__((ext_vector_type(4)));

#define M_TOT 12544          // B*N
#define DIM_  768
#define SCALE_ 0.125f

__device__ __forceinline__ void gload16(const void* g, void* l) {
  __builtin_amdgcn_global_load_lds(
      (__attribute__((address_space(1))) void*)(g),
      (__attribute__((address_space(3))) void*)(l), 16, 0, 0);
}

// ------------------------- weight transpose + cvt --------------------------
// W (K x N fp32, depth-major) -> WT (N x K bf16)
__global__ void transpose_cvt(const float* __restrict__ W, __bf16* __restrict__ WT,
                              int K, int N) {
  __shared__ float t[32][33];
  const size_t zoff = (size_t)blockIdx.z * K * N;
  W  += zoff; WT += zoff;
  const int bx = blockIdx.x * 32;   // n tile
  const int by = blockIdx.y * 32;   // k tile
  for (int j = threadIdx.y; j < 32; j += 8)
    t[j][threadIdx.x] = W[(size_t)(by + j) * N + bx + threadIdx.x];
  __syncthreads();
  for (int j = threadIdx.y; j < 32; j += 8)
    WT[(size_t)(bx + j) * K + by + threadIdx.x] = (__bf16)t[threadIdx.x][j];
}

// ------------------------------- copies ------------------------------------
__global__ void copy_f32(const float* __restrict__ src, float* __restrict__ dst) {
  const int i = blockIdx.x * 256 + threadIdx.x;   // exactly 2408448 float4s
  *(f32x4*)(dst + (size_t)i * 4) = *(const f32x4*)(src + (size_t)i * 4);
}

// ------------------------------ BN stats -----------------------------------
// partial: grid (3, 196); each block: 64 rows x 256 cols
template <typename T>
__global__ void bn_stats_part(const T* __restrict__ x, float* __restrict__ part) {
  const int col = blockIdx.x * 256 + threadIdx.x;
  const int r0  = blockIdx.y * 64;
  const T* p = x + (size_t)r0 * DIM_ + col;
  float s = 0.f, s2 = 0.f;
  for (int r = 0; r < 64; ++r) {
    float v = (float)p[(size_t)r * DIM_];
    s += v; s2 += v * v;
  }
  float* q = part + ((size_t)blockIdx.y * DIM_ + col) * 2;
  q[0] = s; q[1] = s2;
}

__global__ void bn_stats_fin(const float* __restrict__ part, const float* __restrict__ g,
                             const float* __restrict__ b, float* __restrict__ sc) {
  const int col = blockIdx.x * 256 + threadIdx.x;
  float s = 0.f, s2 = 0.f;
  for (int p = 0; p < 196; ++p) {
    s  += part[((size_t)p * DIM_ + col) * 2];
    s2 += part[((size_t)p * DIM_ + col) * 2 + 1];
  }
  const float mean = s * (1.f / 12544.f);
  const float var  = s2 * (1.f / 12544.f) - mean * mean;
  const float rstd = rsqrtf(var + 1e-5f);
  const float scale = rstd * g[col];
  sc[col]        = scale;
  sc[DIM_ + col] = b[col] - mean * scale;
}

// ------------------------------ BN apply -----------------------------------
__global__ void bn_apply_f32(const float* __restrict__ x, const float* __restrict__ sc,
                             __bf16* __restrict__ h) {
  const int i = blockIdx.x * 256 + threadIdx.x;   // exactly 2408448 groups of 4
  const int c4 = i % 192;
  f32x4 v  = *(const f32x4*)(x + (size_t)i * 4);
  f32x4 scl = *(const f32x4*)(sc + c4 * 4);
  f32x4 sh  = *(const f32x4*)(sc + DIM_ + c4 * 4);
  f32x4 y = v * scl + sh;
  bf16x4 o;
  o[0] = (__bf16)y[0]; o[1] = (__bf16)y[1]; o[2] = (__bf16)y[2]; o[3] = (__bf16)y[3];
  *(bf16x4*)(h + (size_t)i * 4) = o;
}

__global__ void bn_gelu_apply(const __bf16* __restrict__ f1, const float* __restrict__ sc,
                              __bf16* __restrict__ h) {
  const int i = blockIdx.x * 256 + threadIdx.x;
  const int c4 = i % 192;
  bf16x4 v4 = *(const bf16x4*)(f1 + (size_t)i * 4);
  f32x4 scl = *(const f32x4*)(sc + c4 * 4);
  f32x4 sh  = *(const f32x4*)(sc + DIM_ + c4 * 4);
  bf16x4 o;
#pragma unroll
  for (int j = 0; j < 4; ++j) {
    float y = (float)v4[j] * scl[j] + sh[j];
    float gl = 0.5f * y * (1.f + erff(y * 0.70710678118654752f));
    o[j] = (__bf16)gl;
  }
  *(bf16x4*)(h + (size_t)i * 4) = o;
}

// -------------------------------- GEMM -------------------------------------
// C[M x N] = A[M x K] @ BT[N x K]^T ; 128x128 tile, BK=64, 256 thr (4 waves 2x2).
// EPI 0: outB = bf16(acc + bias) ; EPI 1: outF += acc + bias (fp32 residual)
template <int EPI>
__global__ __launch_bounds__(256, 2) void gemm128(
    const __bf16* __restrict__ A, int lda,
    const __bf16* __restrict__ BT, int K,
    const float* __restrict__ bias,
    __bf16* __restrict__ outB, float* outF, int ldc) {
  __shared__ __bf16 sA[128 * 64];
  __shared__ __bf16 sB[128 * 64];
  const int tid = threadIdx.x;
  const int lane = tid & 63, wv = tid >> 6;
  const int l15 = lane & 15, hi = lane >> 4;
  const int m0 = blockIdx.x * 128, n0 = blockIdx.y * 128;
  const __bf16* Ab = A + (size_t)m0 * lda;
  const __bf16* Bb = BT + (size_t)n0 * K;
  const int wr = (wv >> 1) * 64, wc = (wv & 1) * 64;

  f32x4 acc[4][4] = {};

  const int nkt = K >> 6;
  for (int kt = 0; kt < nkt; ++kt) {
    if (kt) __syncthreads();
    const int k0 = kt << 6;
#pragma unroll
    for (int i = 0; i < 4; ++i) {
      const int o = i * 4096 + tid * 16;   // byte offset within 16KB tile
      const int row = o >> 7;
      const int ce  = (o & 127) >> 1;      // element within 64-elem row
      gload16(Ab + (size_t)row * lda + (k0 + ce), sA + (i * 2048 + wv * 512));
      gload16(Bb + (size_t)row * K   + (k0 + ce), sB + (i * 2048 + wv * 512));
    }
    asm volatile("s_waitcnt vmcnt(0)" ::: "memory");
    __syncthreads();
#pragma unroll
    for (int ks = 0; ks < 2; ++ks) {
      bf16x8 af[4], bfr[4];
#pragma unroll
      for (int m = 0; m < 4; ++m)
        af[m] = *(const bf16x8*)&sA[(wr + m * 16 + l15) * 64 + ks * 32 + hi * 8];
#pragma unroll
      for (int n = 0; n < 4; ++n)
        bfr[n] = *(const bf16x8*)&sB[(wc + n * 16 + l15) * 64 + ks * 32 + hi * 8];
#pragma unroll
      for (int m = 0; m < 4; ++m)
#pragma unroll
        for (int n = 0; n < 4; ++n)
          acc[m][n] = __builtin_amdgcn_mfma_f32_16x16x32_bf16(af[m], bfr[n], acc[m][n], 0, 0, 0);
    }
  }

#pragma unroll
  for (int m = 0; m < 4; ++m)
#pragma unroll
    for (int n = 0; n < 4; ++n) {
      const int cc = n0 + wc + n * 16 + l15;
      const float bvv = bias[cc];
#pragma unroll
      for (int r = 0; r < 4; ++r) {
        const int rr = m0 + wr + m * 16 + hi * 4 + r;
        const float val = acc[m][n][r] + bvv;
        if (EPI == 0) {
          outB[(size_t)rr * ldc + cc] = (__bf16)val;
        } else {
          float* p = outF + (size_t)rr * ldc + cc;
          *p = *p + val;
        }
      }
    }
}

// ------------------------------ attention ----------------------------------
// One block per (b,h). qk: [12544][1024] bf16 (q cols h*64.., k cols 512+h*64..)
// v: [12544][896] bf16 (cols h*112..). o: same layout as v.
// LDS: sK 208x64 (128B rows, XOR swz), sVT 112 rows x 512B, sP per-wave 16x512B.
__global__ __launch_bounds__(256, 1) void attn_kernel(
    const __bf16* __restrict__ qk, const __bf16* __restrict__ vg,
    __bf16* __restrict__ og) {
  __shared__ __align__(16) char smem[116736];
  const int bh = blockIdx.x, bb = bh >> 3, hh = bh & 7;
  const int tid = threadIdx.x, lane = tid & 63, wv = tid >> 6;
  const int l15 = lane & 15, hi = lane >> 4;

  const __bf16* qbase = qk + (size_t)bb * (196 * 1024) + hh * 64;
  const __bf16* kbase = qbase + 512;
  const __bf16* vbase = vg + (size_t)bb * (196 * 896) + hh * 112;
  __bf16* obase = og + (size_t)bb * (196 * 896) + hh * 112;

  char* sVT = smem + 26624;
  char* sP  = smem + 83968 + wv * 8192;

  // stage K rows (swizzled): byte = j*128 + ((k8*16) ^ ((j&7)<<4))
  for (int c = tid; c < 196 * 8; c += 256) {
    const int n = c >> 3, k8 = c & 7;
    const int ad = n * 128 + ((k8 * 16) ^ ((n & 7) << 4));
    *(bf16x8*)(smem + ad) = *(const bf16x8*)(kbase + (size_t)n * 1024 + k8 * 8);
  }
  {
    bf16x8 z = {};
    for (int c = tid; c < 96; c += 256) {           // zero K rows 196..207
      const int n = 196 + (c >> 3), k8 = c & 7;
      const int ad = n * 128 + ((k8 * 16) ^ ((n & 7) << 4));
      *(bf16x8*)(smem + ad) = z;
    }
  }
  // stage V^T : logical (d, n) at byte d*512 + ((n*2) ^ ((d&7)<<4))
  for (int c = tid; c < 196 * 112; c += 256) {
    const int n = c / 112, d = c - n * 112;
    const int ad = d * 512 + (((n * 2)) ^ ((d & 7) << 4));
    *(__bf16*)(sVT + ad) = vbase[(size_t)n * 896 + d];
  }
  for (int c = tid; c < 112 * 28; c += 256) {       // zero V^T cols 196..223
    const int d = c / 28, n = 196 + (c - d * 28);
    const int ad = d * 512 + (((n * 2)) ^ ((d & 7) << 4));
    *(__bf16*)(sVT + ad) = (__bf16)0.f;
  }
  __syncthreads();

  const int xm = (l15 & 7) << 4;
  for (int qt = wv; qt < 13; qt += 4) {
    const int q0 = qt * 16;
    int qn = q0 + l15; if (qn > 195) qn = 195;
    const __bf16* qp = qbase + (size_t)qn * 1024 + hi * 8;
    const bf16x8 qa0 = *(const bf16x8*)(qp);
    const bf16x8 qa1 = *(const bf16x8*)(qp + 32);

    f32x4 s[13] = {};
#pragma unroll
    for (int nf = 0; nf < 13; ++nf) {
      const int j = nf * 16 + l15;
      const bf16x8 kb0 = *(const bf16x8*)(smem + j * 128 + ((hi * 16) ^ xm));
      const bf16x8 kb1 = *(const bf16x8*)(smem + j * 128 + ((64 + hi * 16) ^ xm));
      s[nf] = __builtin_amdgcn_mfma_f32_16x16x32_bf16(qa0, kb0, s[nf], 0, 0, 0);
      s[nf] = __builtin_amdgcn_mfma_f32_16x16x32_bf16(qa1, kb1, s[nf], 0, 0, 0);
    }

    // softmax: row = hi*4+r, cols spread over l15 (16 lanes) x 13 frags
#pragma unroll
    for (int r = 0; r < 4; ++r) {
      float mx = -3.0e38f;
#pragma unroll
      for (int nf = 0; nf < 12; ++nf) mx = fmaxf(mx, s[nf][r]);
      if (l15 < 4) mx = fmaxf(mx, s[12][r]);
#pragma unroll
      for (int off = 1; off < 16; off <<= 1) mx = fmaxf(mx, __shfl_xor(mx, off));
      float sum = 0.f;
#pragma unroll
      for (int nf = 0; nf < 13; ++nf) {
        const bool valid = (nf < 12) || (l15 < 4);
        const float p = valid ? __expf((s[nf][r] - mx) * SCALE_) : 0.f;
        s[nf][r] = p; sum += p;
      }
#pragma unroll
      for (int off = 1; off < 16; off <<= 1) sum += __shfl_xor(sum, off);
      const float inv = 1.f / sum;
#pragma unroll
      for (int nf = 0; nf < 13; ++nf) s[nf][r] *= inv;
    }

    // write P to per-wave LDS: logical (row, col) at row*512 + ((col*2)^((row&7)<<4))
#pragma unroll
    for (int r = 0; r < 4; ++r) {
      const int row = hi * 4 + r;
      const int rm = (row & 7) << 4;
      char* rp = sP + row * 512;
#pragma unroll
      for (int nf = 0; nf < 13; ++nf)
        *(__bf16*)(rp + (((nf * 16 + l15) * 2) ^ rm)) = (__bf16)s[nf][r];
      *(__bf16*)(rp + (((208 + l15) * 2) ^ rm)) = (__bf16)0.f;   // pad cols 208..223
    }

    // PV: O(16 x 112) = P(16 x 224) @ V(224 x 112)
    f32x4 oa[7] = {};
#pragma unroll
    for (int kk = 0; kk < 7; ++kk) {
      const bf16x8 pa = *(const bf16x8*)(sP + l15 * 512 + ((kk * 64 + hi * 16) ^ xm));
#pragma unroll
      for (int nf = 0; nf < 7; ++nf) {
        const int d = nf * 16 + l15;
        const bf16x8 vbf = *(const bf16x8*)(sVT + d * 512 + ((kk * 64 + hi * 16) ^ xm));
        oa[nf] = __builtin_amdgcn_mfma_f32_16x16x32_bf16(pa, vbf, oa[nf], 0, 0, 0);
      }
    }
#pragma unroll
    for (int nf = 0; nf < 7; ++nf)
#pragma unroll
      for (int r = 0; r < 4; ++r) {
        const int q = q0 + hi * 4 + r;
        if (q < 196) obase[(size_t)q * 896 + nf * 16 + l15] = (__bf16)oa[nf][r];
      }
  }
}

// ------------------------------- launch ------------------------------------
extern "C" void kernel_launch(void* const* d_in, const int* in_sizes, int n_in,
                              void* d_out, int out_size, void* d_ws, size_t ws_size,
                              hipStream_t stream) {
  (void)in_sizes; (void)n_in; (void)out_size; (void)ws_size;
  const float* x_in  = (const float*)d_in[0];
  const float* bn1_g = (const float*)d_in[1];
  const float* bn1_b = (const float*)d_in[2];
  const float* Wqk   = (const float*)d_in[3];
  const float* bqk   = (const float*)d_in[4];
  const float* Wv    = (const float*)d_in[5];
  const float* bv    = (const float*)d_in[6];
  const float* Wo    = (const float*)d_in[7];
  const float* bo    = (const float*)d_in[8];
  const float* bn2_g = (const float*)d_in[9];
  const float* bn2_b = (const float*)d_in[10];
  const float* W1    = (const float*)d_in[11];
  const float* b1    = (const float*)d_in[12];
  const float* bn3_g = (const float*)d_in[13];
  const float* bn3_b = (const float*)d_in[14];
  const float* W2    = (const float*)d_in[15];
  const float* b2    = (const float*)d_in[16];

  char* ws = (char*)d_ws;
  float*  xb   = (float*)(ws + 0);            // 12544x768 f32
  __bf16* wqkT = (__bf16*)(ws + 38535168);    // 6 x 1024 x 384
  __bf16* wvT  = (__bf16*)(ws + 43253760);    // 6 x 896 x 768
  __bf16* woT  = (__bf16*)(ws + 51511296);    // 6 x 768 x 896
  __bf16* w1T  = (__bf16*)(ws + 59768832);    // 6 x 768 x 768
  __bf16* w2T  = (__bf16*)(ws + 66846720);    // 6 x 768 x 768
  __bf16* hb   = (__bf16*)(ws + 73924608);    // 12544x768 bf16
  __bf16* qkb  = (__bf16*)(ws + 93192192);    // 12544x1024 bf16 (also f1 reuse)
  __bf16* vbuf = (__bf16*)(ws + 118882304);   // 12544x896 bf16
  __bf16* obuf = (__bf16*)(ws + 141361152);   // 12544x896 bf16
  float*  part = (float*)(ws + 163840000);    // 196x768x2 f32
  float*  sc   = (float*)(ws + 165044224);    // 2x768 f32
  __bf16* f1b  = qkb;

  const dim3 tb(256);

  transpose_cvt<<<dim3(32, 12, 6), dim3(32, 8), 0, stream>>>(Wqk, wqkT, 384, 1024);
  transpose_cvt<<<dim3(28, 24, 6), dim3(32, 8), 0, stream>>>(Wv,  wvT,  768, 896);
  transpose_cvt<<<dim3(24, 28, 6), dim3(32, 8), 0, stream>>>(Wo,  woT,  896, 768);
  transpose_cvt<<<dim3(24, 24, 6), dim3(32, 8), 0, stream>>>(W1,  w1T,  768, 768);
  transpose_cvt<<<dim3(24, 24, 6), dim3(32, 8), 0, stream>>>(W2,  w2T,  768, 768);
  copy_f32<<<9408, tb, 0, stream>>>(x_in, xb);

  for (int i = 0; i < 6; ++i) {
    const __bf16* wqkT_i = wqkT + (size_t)i * 1024 * 384;
    const __bf16* wvT_i  = wvT  + (size_t)i * 896 * 768;
    const __bf16* woT_i  = woT  + (size_t)i * 768 * 896;
    const __bf16* w1T_i  = w1T  + (size_t)i * 768 * 768;
    const __bf16* w2T_i  = w2T  + (size_t)i * 768 * 768;

    // --- attention block ---
    bn_stats_part<float><<<dim3(3, 196), tb, 0, stream>>>(xb, part);
    bn_stats_fin<<<3, tb, 0, stream>>>(part, bn1_g + i * 768, bn1_b + i * 768, sc);
    bn_apply_f32<<<9408, tb, 0, stream>>>(xb, sc, hb);
    gemm128<0><<<dim3(98, 8), tb, 0, stream>>>(hb + 384, 768, wqkT_i, 384,
                                               bqk + i * 1024, qkb, nullptr, 1024);
    gemm128<0><<<dim3(98, 7), tb, 0, stream>>>(hb, 768, wvT_i, 768,
                                               bv + i * 896, vbuf, nullptr, 896);
    attn_kernel<<<512, tb, 0, stream>>>(qkb, vbuf, obuf);
    gemm128<1><<<dim3(98, 6), tb, 0, stream>>>(obuf, 896, woT_i, 896,
                                               bo + i * 768, nullptr, xb, 768);

    // --- feedforward block ---
    bn_stats_part<float><<<dim3(3, 196), tb, 0, stream>>>(xb, part);
    bn_stats_fin<<<3, tb, 0, stream>>>(part, bn2_g + i * 768, bn2_b + i * 768, sc);
    bn_apply_f32<<<9408, tb, 0, stream>>>(xb, sc, hb);
    gemm128<0><<<dim3(98, 6), tb, 0, stream>>>(hb, 768, w1T_i, 768,
                                               b1 + i * 768, f1b, nullptr, 768);
    bn_stats_part<__bf16><<<dim3(3, 196), tb, 0, stream>>>(f1b, part);
    bn_stats_fin<<<3, tb, 0, stream>>>(part, bn3_g + i * 768, bn3_b + i * 768, sc);
    bn_gelu_apply<<<9408, tb, 0, stream>>>(f1b, sc, hb);
    gemm128<1><<<dim3(98, 6), tb, 0, stream>>>(hb, 768, w2T_i, 768,
                                               b2 + i * 768, nullptr, xb, 768);
  }
  copy_f32<<<9408, tb, 0, stream>>>(xb, (float*)d_out);
}

// Round 3
// 1800.425 us; speedup vs baseline: 1.0617x; 1.0617x over previous
//
#include <hip/hip_runtime.h>
#include <hip/hip_bf16.h>
#include <stdint.h>

// ---------------------------------------------------------------------------
// Transformer: 6 layers. fp32 residual stream + BN stats; bf16 MFMA GEMMs.
// R3: attention with V^T produced by GEMM, 8-wave attn blocks, gload_lds K
// staging, XOR-swizzled LDS at pitch 512 (bijective within each row).
// ---------------------------------------------------------------------------

typedef __bf16 bf16x8 __attribute__((ext_vector_type(8)));
typedef __bf16 bf16x4 __attribute__((ext_vector_type(4)));
typedef float  f32x4  __attribute__((ext_vector_type(4)));

#define DIM_  768
#define SCALE_ 0.125f

__device__ __forceinline__ void gload16(const void* g, void* l) {
  __builtin_amdgcn_global_load_lds(
      (__attribute__((address_space(1))) void*)(g),
      (__attribute__((address_space(3))) void*)(l), 16, 0, 0);
}

// ------------------------- weight transpose + cvt --------------------------
__global__ void transpose_cvt(const float* __restrict__ W, __bf16* __restrict__ WT,
                              int K, int N) {
  __shared__ float t[32][33];
  const size_t zoff = (size_t)blockIdx.z * K * N;
  W  += zoff; WT += zoff;
  const int bx = blockIdx.x * 32;
  const int by = blockIdx.y * 32;
  for (int j = threadIdx.y; j < 32; j += 8)
    t[j][threadIdx.x] = W[(size_t)(by + j) * N + bx + threadIdx.x];
  __syncthreads();
  for (int j = threadIdx.y; j < 32; j += 8)
    WT[(size_t)(bx + j) * K + by + threadIdx.x] = (__bf16)t[threadIdx.x][j];
}

// ------------------------------- copies ------------------------------------
__global__ void copy_f32(const float* __restrict__ src, float* __restrict__ dst) {
  const int i = blockIdx.x * 256 + threadIdx.x;
  *(f32x4*)(dst + (size_t)i * 4) = *(const f32x4*)(src + (size_t)i * 4);
}

// ------------------------------ BN stats -----------------------------------
template <typename T>
__global__ void bn_stats_part(const T* __restrict__ x, float* __restrict__ part) {
  const int col = blockIdx.x * 256 + threadIdx.x;
  const int r0  = blockIdx.y * 64;
  const T* p = x + (size_t)r0 * DIM_ + col;
  float s = 0.f, s2 = 0.f;
  for (int r = 0; r < 64; ++r) {
    float v = (float)p[(size_t)r * DIM_];
    s += v; s2 += v * v;
  }
  float* q = part + ((size_t)blockIdx.y * DIM_ + col) * 2;
  q[0] = s; q[1] = s2;
}

__global__ void bn_stats_fin(const float* __restrict__ part, const float* __restrict__ g,
                             const float* __restrict__ b, float* __restrict__ sc) {
  const int col = blockIdx.x * 256 + threadIdx.x;
  float s = 0.f, s2 = 0.f;
  for (int p = 0; p < 196; ++p) {
    s  += part[((size_t)p * DIM_ + col) * 2];
    s2 += part[((size_t)p * DIM_ + col) * 2 + 1];
  }
  const float mean = s * (1.f / 12544.f);
  const float var  = s2 * (1.f / 12544.f) - mean * mean;
  const float rstd = rsqrtf(var + 1e-5f);
  const float scale = rstd * g[col];
  sc[col]        = scale;
  sc[DIM_ + col] = b[col] - mean * scale;
}

// ------------------------------ BN apply -----------------------------------
__global__ void bn_apply_f32(const float* __restrict__ x, const float* __restrict__ sc,
                             __bf16* __restrict__ h) {
  const int i = blockIdx.x * 256 + threadIdx.x;
  const int c4 = i % 192;
  f32x4 v  = *(const f32x4*)(x + (size_t)i * 4);
  f32x4 scl = *(const f32x4*)(sc + c4 * 4);
  f32x4 sh  = *(const f32x4*)(sc + DIM_ + c4 * 4);
  f32x4 y = v * scl + sh;
  bf16x4 o;
  o[0] = (__bf16)y[0]; o[1] = (__bf16)y[1]; o[2] = (__bf16)y[2]; o[3] = (__bf16)y[3];
  *(bf16x4*)(h + (size_t)i * 4) = o;
}

__global__ void bn_gelu_apply(const __bf16* __restrict__ f1, const float* __restrict__ sc,
                              __bf16* __restrict__ h) {
  const int i = blockIdx.x * 256 + threadIdx.x;
  const int c4 = i % 192;
  bf16x4 v4 = *(const bf16x4*)(f1 + (size_t)i * 4);
  f32x4 scl = *(const f32x4*)(sc + c4 * 4);
  f32x4 sh  = *(const f32x4*)(sc + DIM_ + c4 * 4);
  bf16x4 o;
#pragma unroll
  for (int j = 0; j < 4; ++j) {
    float y = (float)v4[j] * scl[j] + sh[j];
    float gl = 0.5f * y * (1.f + erff(y * 0.70710678118654752f));
    o[j] = (__bf16)gl;
  }
  *(bf16x4*)(h + (size_t)i * 4) = o;
}

// -------------------------------- GEMM -------------------------------------
// C[M x N] = A[M x K] @ BT[N x K]^T ; 128x128 tile, BK=64, 256 thr (4 waves).
// EPI 0: outB = bf16(acc + bias[col]); EPI 1: outF += acc + bias[col];
// EPI 2: outB = bf16(acc + bias[row])   (for producing V^T)
template <int EPI>
__global__ __launch_bounds__(256, 2) void gemm128(
    const __bf16* __restrict__ A, int lda,
    const __bf16* __restrict__ BT, int K,
    const float* __restrict__ bias,
    __bf16* __restrict__ outB, float* outF, int ldc) {
  __shared__ __bf16 sA[128 * 64];
  __shared__ __bf16 sB[128 * 64];
  const int tid = threadIdx.x;
  const int lane = tid & 63, wv = tid >> 6;
  const int l15 = lane & 15, hi = lane >> 4;
  const int m0 = blockIdx.x * 128, n0 = blockIdx.y * 128;
  const __bf16* Ab = A + (size_t)m0 * lda;
  const __bf16* Bb = BT + (size_t)n0 * K;
  const int wr = (wv >> 1) * 64, wc = (wv & 1) * 64;

  f32x4 acc[4][4] = {};

  const int nkt = K >> 6;
  for (int kt = 0; kt < nkt; ++kt) {
    if (kt) __syncthreads();
    const int k0 = kt << 6;
#pragma unroll
    for (int i = 0; i < 4; ++i) {
      const int o = i * 4096 + tid * 16;
      const int row = o >> 7;
      const int ce  = (o & 127) >> 1;
      gload16(Ab + (size_t)row * lda + (k0 + ce), sA + (i * 2048 + wv * 512));
      gload16(Bb + (size_t)row * K   + (k0 + ce), sB + (i * 2048 + wv * 512));
    }
    asm volatile("s_waitcnt vmcnt(0)" ::: "memory");
    __syncthreads();
#pragma unroll
    for (int ks = 0; ks < 2; ++ks) {
      bf16x8 af[4], bfr[4];
#pragma unroll
      for (int m = 0; m < 4; ++m)
        af[m] = *(const bf16x8*)&sA[(wr + m * 16 + l15) * 64 + ks * 32 + hi * 8];
#pragma unroll
      for (int n = 0; n < 4; ++n)
        bfr[n] = *(const bf16x8*)&sB[(wc + n * 16 + l15) * 64 + ks * 32 + hi * 8];
#pragma unroll
      for (int m = 0; m < 4; ++m)
#pragma unroll
        for (int n = 0; n < 4; ++n)
          acc[m][n] = __builtin_amdgcn_mfma_f32_16x16x32_bf16(af[m], bfr[n], acc[m][n], 0, 0, 0);
    }
  }

#pragma unroll
  for (int m = 0; m < 4; ++m)
#pragma unroll
    for (int n = 0; n < 4; ++n) {
      const int cc = n0 + wc + n * 16 + l15;
      const float bc = (EPI == 2) ? 0.f : bias[cc];
#pragma unroll
      for (int r = 0; r < 4; ++r) {
        const int rr = m0 + wr + m * 16 + hi * 4 + r;
        const float val = acc[m][n][r] + ((EPI == 2) ? bias[rr] : bc);
        if (EPI == 1) {
          float* p = outF + (size_t)rr * ldc + cc;
          *p = *p + val;
        } else {
          outB[(size_t)rr * ldc + cc] = (__bf16)val;
        }
      }
    }
}

// ------------------------------ attention ----------------------------------
// One block per (b,h), 512 threads (8 waves). qk: [12544][1024] bf16
// (q cols h*64.., k cols 512+h*64..). vT: [896][12544] bf16 (row h*112+d,
// col b*196+n). o: [12544][896] bf16.
// LDS: sK 208 rows x 128B (gload to linear dest, pre-swizzled global source;
//      read swz: chunk ^ (row&7));
//      sV 112 rows x 512B  (byte-in-row ^ ((d&7)<<4), bijective: bits 4-6);
//      sP per-wave 16 rows x 512B (same swizzle).
#define SV_OFF 26624
#define SP_OFF 83968
__global__ __launch_bounds__(512, 1) void attn_kernel(
    const __bf16* __restrict__ qk, const __bf16* __restrict__ vT,
    __bf16* __restrict__ og) {
  __shared__ __align__(16) char smem[149504];
  const int bh = blockIdx.x, bb = bh >> 3, hh = bh & 7;
  const int tid = threadIdx.x, lane = tid & 63, wv = tid >> 6;
  const int l15 = lane & 15, hi = lane >> 4;

  const __bf16* qbase = qk + (size_t)bb * (196 * 1024) + hh * 64;
  const __bf16* kbase = qbase + 512;
  const __bf16* vbase = vT + (size_t)(hh * 112) * 12544 + bb * 196;
  __bf16* obase = og + (size_t)bb * (196 * 896) + hh * 112;

  char* sV = smem + SV_OFF;
  char* sP = smem + SP_OFF + wv * 8192;

  // ---- stage K via global_load_lds: slot s=(n,j) holds global chunk j^(n&7)
  for (int s = tid; s < 1664; s += 512) {
    const int n = s >> 3, j = s & 7;
    const int row = (n < 196) ? n : 195;
    const int k8 = j ^ (n & 7);
    gload16(kbase + (size_t)row * 1024 + k8 * 8, smem + ((s >> 6) << 10));
  }
  // ---- stage V^T rows (8B chunks, 49 per row), swizzled ds_write
  for (int c = tid; c < 112 * 49; c += 512) {
    const int d = c / 49, c8 = c - d * 49;
    const bf16x4 v4 = *(const bf16x4*)(vbase + (size_t)d * 12544 + c8 * 4);
    *(bf16x4*)(sV + d * 512 + ((c8 * 8) ^ ((d & 7) << 4))) = v4;
  }
  // ---- zero V pad cols 196..223 (chunks 49..55)
  {
    bf16x4 z = {};
    for (int c = tid; c < 112 * 7; c += 512) {
      const int d = c / 7, c8 = 49 + (c - d * 7);
      *(bf16x4*)(sV + d * 512 + ((c8 * 8) ^ ((d & 7) << 4))) = z;
    }
  }
  asm volatile("s_waitcnt vmcnt(0)" ::: "memory");
  __syncthreads();

  const int xm = (l15 & 7) << 4;
  for (int qt = wv; qt < 13; qt += 8) {
    const int q0 = qt * 16;
    int qn = q0 + l15; if (qn > 195) qn = 195;
    const __bf16* qp = qbase + (size_t)qn * 1024 + hi * 8;
    const bf16x8 qa0 = *(const bf16x8*)(qp);
    const bf16x8 qa1 = *(const bf16x8*)(qp + 32);

    f32x4 s[13] = {};
#pragma unroll
    for (int nf = 0; nf < 13; ++nf) {
      const int j = nf * 16 + l15;
      const bf16x8 kb0 = *(const bf16x8*)(smem + j * 128 + ((hi * 16) ^ xm));
      const bf16x8 kb1 = *(const bf16x8*)(smem + j * 128 + ((64 + hi * 16) ^ xm));
      s[nf] = __builtin_amdgcn_mfma_f32_16x16x32_bf16(qa0, kb0, s[nf], 0, 0, 0);
      s[nf] = __builtin_amdgcn_mfma_f32_16x16x32_bf16(qa1, kb1, s[nf], 0, 0, 0);
    }

    // softmax over k (cols spread across l15 x 13 frags); rows hi*4+r
#pragma unroll
    for (int r = 0; r < 4; ++r) {
      float mx = -3.0e38f;
#pragma unroll
      for (int nf = 0; nf < 12; ++nf) mx = fmaxf(mx, s[nf][r]);
      if (l15 < 4) mx = fmaxf(mx, s[12][r]);
#pragma unroll
      for (int off = 1; off < 16; off <<= 1) mx = fmaxf(mx, __shfl_xor(mx, off));
      float sum = 0.f;
#pragma unroll
      for (int nf = 0; nf < 13; ++nf) {
        const bool valid = (nf < 12) || (l15 < 4);
        const float p = valid ? __expf((s[nf][r] - mx) * SCALE_) : 0.f;
        s[nf][r] = p; sum += p;
      }
#pragma unroll
      for (int off = 1; off < 16; off <<= 1) sum += __shfl_xor(sum, off);
      const float inv = 1.f / sum;
#pragma unroll
      for (int nf = 0; nf < 13; ++nf) s[nf][r] *= inv;
    }

    // write P (bf16) to per-wave LDS, swizzled pitch 512
#pragma unroll
    for (int r = 0; r < 4; ++r) {
      const int row = hi * 4 + r;
      const int rm = (row & 7) << 4;
      char* rp = sP + row * 512;
#pragma unroll
      for (int nf = 0; nf < 13; ++nf)
        *(__bf16*)(rp + (((nf * 16 + l15) * 2) ^ rm)) = (__bf16)s[nf][r];
      *(__bf16*)(rp + (((208 + l15) * 2) ^ rm)) = (__bf16)0.f;
    }

    // PV: O(16 x 112) = P(16 x 224) @ V^T(112 x 224)^T
    f32x4 oa[7] = {};
#pragma unroll
    for (int kk = 0; kk < 7; ++kk) {
      const bf16x8 pa = *(const bf16x8*)(sP + l15 * 512 + ((kk * 64 + hi * 16) ^ xm));
#pragma unroll
      for (int nf = 0; nf < 7; ++nf) {
        const int d = nf * 16 + l15;
        const bf16x8 vbf = *(const bf16x8*)(sV + d * 512 + ((kk * 64 + hi * 16) ^ xm));
        oa[nf] = __builtin_amdgcn_mfma_f32_16x16x32_bf16(pa, vbf, oa[nf], 0, 0, 0);
      }
    }
#pragma unroll
    for (int nf = 0; nf < 7; ++nf)
#pragma unroll
      for (int r = 0; r < 4; ++r) {
        const int q = q0 + hi * 4 + r;
        if (q < 196) obase[(size_t)q * 896 + nf * 16 + l15] = (__bf16)oa[nf][r];
      }
  }
}

// ------------------------------- launch ------------------------------------
extern "C" void kernel_launch(void* const* d_in, const int* in_sizes, int n_in,
                              void* d_out, int out_size, void* d_ws, size_t ws_size,
                              hipStream_t stream) {
  (void)in_sizes; (void)n_in; (void)out_size; (void)ws_size;
  const float* x_in  = (const float*)d_in[0];
  const float* bn1_g = (const float*)d_in[1];
  const float* bn1_b = (const float*)d_in[2];
  const float* Wqk   = (const float*)d_in[3];
  const float* bqk   = (const float*)d_in[4];
  const float* Wv    = (const float*)d_in[5];
  const float* bv    = (const float*)d_in[6];
  const float* Wo    = (const float*)d_in[7];
  const float* bo    = (const float*)d_in[8];
  const float* bn2_g = (const float*)d_in[9];
  const float* bn2_b = (const float*)d_in[10];
  const float* W1    = (const float*)d_in[11];
  const float* b1    = (const float*)d_in[12];
  const float* bn3_g = (const float*)d_in[13];
  const float* bn3_b = (const float*)d_in[14];
  const float* W2    = (const float*)d_in[15];
  const float* b2    = (const float*)d_in[16];

  char* ws = (char*)d_ws;
  float*  xb   = (float*)(ws + 0);            // 12544x768 f32
  __bf16* wqkT = (__bf16*)(ws + 38535168);    // 6 x 1024 x 384
  __bf16* wvT  = (__bf16*)(ws + 43253760);    // 6 x 896 x 768
  __bf16* woT  = (__bf16*)(ws + 51511296);    // 6 x 768 x 896
  __bf16* w1T  = (__bf16*)(ws + 59768832);    // 6 x 768 x 768
  __bf16* w2T  = (__bf16*)(ws + 66846720);    // 6 x 768 x 768
  __bf16* hb   = (__bf16*)(ws + 73924608);    // 12544x768 bf16
  __bf16* qkb  = (__bf16*)(ws + 93192192);    // 12544x1024 bf16 (also f1 reuse)
  __bf16* vTb  = (__bf16*)(ws + 118882304);   // 896x12544 bf16 (V^T)
  __bf16* obuf = (__bf16*)(ws + 141361152);   // 12544x896 bf16
  float*  part = (float*)(ws + 163840000);    // 196x768x2 f32
  float*  sc   = (float*)(ws + 165044224);    // 2x768 f32
  __bf16* f1b  = qkb;

  const dim3 tb(256);

  transpose_cvt<<<dim3(32, 12, 6), dim3(32, 8), 0, stream>>>(Wqk, wqkT, 384, 1024);
  transpose_cvt<<<dim3(28, 24, 6), dim3(32, 8), 0, stream>>>(Wv,  wvT,  768, 896);
  transpose_cvt<<<dim3(24, 28, 6), dim3(32, 8), 0, stream>>>(Wo,  woT,  896, 768);
  transpose_cvt<<<dim3(24, 24, 6), dim3(32, 8), 0, stream>>>(W1,  w1T,  768, 768);
  transpose_cvt<<<dim3(24, 24, 6), dim3(32, 8), 0, stream>>>(W2,  w2T,  768, 768);
  copy_f32<<<9408, tb, 0, stream>>>(x_in, xb);

  for (int i = 0; i < 6; ++i) {
    const __bf16* wqkT_i = wqkT + (size_t)i * 1024 * 384;
    const __bf16* wvT_i  = wvT  + (size_t)i * 896 * 768;
    const __bf16* woT_i  = woT  + (size_t)i * 768 * 896;
    const __bf16* w1T_i  = w1T  + (size_t)i * 768 * 768;
    const __bf16* w2T_i  = w2T  + (size_t)i * 768 * 768;

    // --- attention block ---
    bn_stats_part<float><<<dim3(3, 196), tb, 0, stream>>>(xb, part);
    bn_stats_fin<<<3, tb, 0, stream>>>(part, bn1_g + i * 768, bn1_b + i * 768, sc);
    bn_apply_f32<<<9408, tb, 0, stream>>>(xb, sc, hb);
    gemm128<0><<<dim3(98, 8), tb, 0, stream>>>(hb + 384, 768, wqkT_i, 384,
                                               bqk + i * 1024, qkb, nullptr, 1024);
    // V^T[896][12544] = Wv^T @ h^T  (row bias)
    gemm128<2><<<dim3(7, 98), tb, 0, stream>>>(wvT_i, 768, hb, 768,
                                               bv + i * 896, vTb, nullptr, 12544);
    attn_kernel<<<512, dim3(512), 0, stream>>>(qkb, vTb, obuf);
    gemm128<1><<<dim3(98, 6), tb, 0, stream>>>(obuf, 896, woT_i, 896,
                                               bo + i * 768, nullptr, xb, 768);

    // --- feedforward block ---
    bn_stats_part<float><<<dim3(3, 196), tb, 0, stream>>>(xb, part);
    bn_stats_fin<<<3, tb, 0, stream>>>(part, bn2_g + i * 768, bn2_b + i * 768, sc);
    bn_apply_f32<<<9408, tb, 0, stream>>>(xb, sc, hb);
    gemm128<0><<<dim3(98, 6), tb, 0, stream>>>(hb, 768, w1T_i, 768,
                                               b1 + i * 768, f1b, nullptr, 768);
    bn_stats_part<__bf16><<<dim3(3, 196), tb, 0, stream>>>(f1b, part);
    bn_stats_fin<<<3, tb, 0, stream>>>(part, bn3_g + i * 768, bn3_b + i * 768, sc);
    bn_gelu_apply<<<9408, tb, 0, stream>>>(f1b, sc, hb);
    gemm128<1><<<dim3(98, 6), tb, 0, stream>>>(hb, 768, w2T_i, 768,
                                               b2 + i * 768, nullptr, xb, 768);
  }
  copy_f32<<<9408, tb, 0, stream>>>(xb, (float*)d_out);
}